// Round 2
// baseline (250.762 us; speedup 1.0000x reference)
//
#include <hip/hip_runtime.h>

// CMOW word-matrix chain product — R2.
// sent:  [1024, 64] int32 ; table: [30001, 784] fp32 ; out: [1024, 784] fp32
//
// One block (4 waves) per batch row; each wave owns a 16-matrix chunk and a
// private in-place LDS buffer holding `cur` (col-major, stride 28).
// Phase 1 has NO block barriers: waves are independent; in-wave ordering via
// s_waitcnt lgkmcnt(0) + compiler memory barrier.
// B is read straight from global (L1/L2 cached; 7 lanes share each address),
// eliminating all LDS staging. A-reads are 7-address broadcast b128 reads.
// 49 active lanes, 4x4 register tiles.

#define MD    28
#define MD2   784
#define SEQL  64
#define CHUNK 16

#define LDS_FENCE() asm volatile("s_waitcnt lgkmcnt(0)" ::: "memory")

// A, B col-major stride 28 in LDS; acc += (A@B)[r0:+4][c0:+4]
__device__ __forceinline__ void matmul_lds(const float* __restrict__ A,
                                           const float* __restrict__ B,
                                           float acc[4][4], int r0, int c0) {
    #pragma unroll
    for (int k0 = 0; k0 < MD; k0 += 4) {
        float4 a0 = *(const float4*)(A + (k0 + 0) * MD + r0);
        float4 a1 = *(const float4*)(A + (k0 + 1) * MD + r0);
        float4 a2 = *(const float4*)(A + (k0 + 2) * MD + r0);
        float4 a3 = *(const float4*)(A + (k0 + 3) * MD + r0);
        float4 b0 = *(const float4*)(B + (c0 + 0) * MD + k0);
        float4 b1 = *(const float4*)(B + (c0 + 1) * MD + k0);
        float4 b2 = *(const float4*)(B + (c0 + 2) * MD + k0);
        float4 b3 = *(const float4*)(B + (c0 + 3) * MD + k0);
        acc[0][0] += a0.x*b0.x + a1.x*b0.y + a2.x*b0.z + a3.x*b0.w;
        acc[1][0] += a0.y*b0.x + a1.y*b0.y + a2.y*b0.z + a3.y*b0.w;
        acc[2][0] += a0.z*b0.x + a1.z*b0.y + a2.z*b0.z + a3.z*b0.w;
        acc[3][0] += a0.w*b0.x + a1.w*b0.y + a2.w*b0.z + a3.w*b0.w;
        acc[0][1] += a0.x*b1.x + a1.x*b1.y + a2.x*b1.z + a3.x*b1.w;
        acc[1][1] += a0.y*b1.x + a1.y*b1.y + a2.y*b1.z + a3.y*b1.w;
        acc[2][1] += a0.z*b1.x + a1.z*b1.y + a2.z*b1.z + a3.z*b1.w;
        acc[3][1] += a0.w*b1.x + a1.w*b1.y + a2.w*b1.z + a3.w*b1.w;
        acc[0][2] += a0.x*b2.x + a1.x*b2.y + a2.x*b2.z + a3.x*b2.w;
        acc[1][2] += a0.y*b2.x + a1.y*b2.y + a2.y*b2.z + a3.y*b2.w;
        acc[2][2] += a0.z*b2.x + a1.z*b2.y + a2.z*b2.z + a3.z*b2.w;
        acc[3][2] += a0.w*b2.x + a1.w*b2.y + a2.w*b2.z + a3.w*b2.w;
        acc[0][3] += a0.x*b3.x + a1.x*b3.y + a2.x*b3.z + a3.x*b3.w;
        acc[1][3] += a0.y*b3.x + a1.y*b3.y + a2.y*b3.z + a3.y*b3.w;
        acc[2][3] += a0.z*b3.x + a1.z*b3.y + a2.z*b3.z + a3.z*b3.w;
        acc[3][3] += a0.w*b3.x + a1.w*b3.y + a2.w*b3.z + a3.w*b3.w;
    }
}

__global__ __launch_bounds__(256, 4)
void cmow_chain_kernel(const int* __restrict__ sent,
                       const float* __restrict__ table,
                       float* __restrict__ out)
{
    // one 784-float col-major buffer per wave
    __shared__ float lds[4 * MD2];

    const int tid  = threadIdx.x;
    const int lane = tid & 63;
    const int b    = blockIdx.x;

    // wave id forced scalar so index loads become s_load
    const int w = __builtin_amdgcn_readfirstlane(tid >> 6);
    float* cur = &lds[w * MD2];

    // ---- chunk indices -> SGPRs
    const int* sp = sent + b * SEQL + w * CHUNK;
    int idx[CHUNK];
    #pragma unroll
    for (int i = 0; i < CHUNK; ++i) idx[i] = sp[i];

    const int  r0     = ((lane / 7) & 7) * 4;   // 0..24
    const int  c0     = (lane % 7) * 4;         // 0..24
    const bool active = (lane < 49);

    // ---- stage first matrix transposed (col-major) into cur
    {
        const float4* m4 = (const float4*)(table + (size_t)idx[0] * MD2);
        for (int e4 = lane; e4 < 196; e4 += 64) {
            float4 v = m4[e4];
            int lin = e4 * 4;
            int r = lin / MD, c = lin % MD;   // c in {0,4,...,24}: stays in row
            cur[(c + 0) * MD + r] = v.x;
            cur[(c + 1) * MD + r] = v.y;
            cur[(c + 2) * MD + r] = v.z;
            cur[(c + 3) * MD + r] = v.w;
        }
    }
    LDS_FENCE();

    // ---- phase 1: 15 in-place chained matmuls, B straight from global
    for (int i = 1; i < CHUNK; ++i) {
        const float* Bg = table + (size_t)idx[i] * MD2;   // scalar base
        float acc[4][4];
        #pragma unroll
        for (int ri = 0; ri < 4; ++ri)
            #pragma unroll
            for (int ci = 0; ci < 4; ++ci) acc[ri][ci] = 0.f;

        if (active) {
            #pragma unroll
            for (int k = 0; k < MD; ++k) {
                const float4 a  = *(const float4*)(cur + k * MD + r0);  // broadcast b128
                const float4 bb = *(const float4*)(Bg  + k * MD + c0);  // global, imm offset
                acc[0][0] += a.x*bb.x; acc[0][1] += a.x*bb.y; acc[0][2] += a.x*bb.z; acc[0][3] += a.x*bb.w;
                acc[1][0] += a.y*bb.x; acc[1][1] += a.y*bb.y; acc[1][2] += a.y*bb.z; acc[1][3] += a.y*bb.w;
                acc[2][0] += a.z*bb.x; acc[2][1] += a.z*bb.y; acc[2][2] += a.z*bb.z; acc[2][3] += a.z*bb.w;
                acc[3][0] += a.w*bb.x; acc[3][1] += a.w*bb.y; acc[3][2] += a.w*bb.z; acc[3][3] += a.w*bb.w;
            }
            // in-place write-back (every write's data depends on ALL A-reads,
            // and per-wave DS ops are in-order -> no WAR hazard)
            #pragma unroll
            for (int ci = 0; ci < 4; ++ci) {
                float4 col;
                col.x = acc[0][ci]; col.y = acc[1][ci]; col.z = acc[2][ci]; col.w = acc[3][ci];
                *(float4*)(cur + (c0 + ci) * MD + r0) = col;
            }
        }
        LDS_FENCE();   // drain writes before next iteration's reads
    }

    // ---- phase 2: tree-combine the 4 chunk products
    __syncthreads();

    if (w < 2 && active) {     // wave0: P0@P1 -> buf0 ; wave1: P2@P3 -> buf2
        float* A = &lds[(2 * w)     * MD2];
        float* B = &lds[(2 * w + 1) * MD2];
        float acc[4][4];
        #pragma unroll
        for (int ri = 0; ri < 4; ++ri)
            #pragma unroll
            for (int ci = 0; ci < 4; ++ci) acc[ri][ci] = 0.f;
        matmul_lds(A, B, acc, r0, c0);
        #pragma unroll
        for (int ci = 0; ci < 4; ++ci) {
            float4 col;
            col.x = acc[0][ci]; col.y = acc[1][ci]; col.z = acc[2][ci]; col.w = acc[3][ci];
            *(float4*)(A + (c0 + ci) * MD + r0) = col;   // in-place over A: safe
        }
    }
    __syncthreads();

    if (w == 0 && active) {    // final = buf0 @ buf2 -> out (row-major)
        const float* A = &lds[0];
        const float* B = &lds[2 * MD2];
        float acc[4][4];
        #pragma unroll
        for (int ri = 0; ri < 4; ++ri)
            #pragma unroll
            for (int ci = 0; ci < 4; ++ci) acc[ri][ci] = 0.f;
        matmul_lds(A, B, acc, r0, c0);
        float* op = out + (size_t)b * MD2;
        #pragma unroll
        for (int ri = 0; ri < 4; ++ri) {
            float4 row;
            row.x = acc[ri][0]; row.y = acc[ri][1]; row.z = acc[ri][2]; row.w = acc[ri][3];
            *(float4*)(op + (r0 + ri) * MD + c0) = row;
        }
    }
}

extern "C" void kernel_launch(void* const* d_in, const int* in_sizes, int n_in,
                              void* d_out, int out_size, void* d_ws, size_t ws_size,
                              hipStream_t stream) {
    const int*   sent  = (const int*)d_in[0];
    const float* table = (const float*)d_in[1];
    float*       outp  = (float*)d_out;

    const int batch = in_sizes[0] / SEQL;   // 1024
    cmow_chain_kernel<<<dim3(batch), dim3(256), 0, stream>>>(sent, table, outp);
}

// Round 4
// 197.186 us; speedup vs baseline: 1.2717x; 1.2717x over previous
//
#include <hip/hip_runtime.h>

// CMOW word-matrix chain product — R4: MFMA bf16x3, phase-2 layout fix.
// sent: [1024,64] int32 ; table: [30001,784] fp32 ; out: [1024,784] fp32
//
// Chain kept TRANSPOSED: X = cur^T, step X_new = M^T @ X via
// mfma_f32_16x16x32_bf16 on 32x32 zero-padded tiles (2x2 output tiles).
// fp32 emulated as hi+lo bf16, 3 products per tile pair.
//
// LDS plane conventions (per 1024-short plane, logical 32x32):
//   A-conv: L[slot=first][pos=second]  (read as A operand: A[m=slot][k=pos])
//   B-conv: L[slot=second][pos=first]  (read as B operand: B[k=pos][n=slot])
// Physical: slot s, pos p -> (s>>4)*512 + (s&15)*32 + (((p>>3)^(s&3))<<3) + (p&7)
// Phase-2 fix vs R3: operands for the tree-combine are written in the
// convention they'll be READ in (R3 wrongly reused B-conv planes as A).

#define MD    28
#define MD2   784
#define SEQL  64
#define CHUNK 16

typedef __attribute__((ext_vector_type(8))) short bf16x8;
typedef __attribute__((ext_vector_type(4))) float floatx4;

#define LDS_FENCE() asm volatile("s_waitcnt lgkmcnt(0)" ::: "memory")

__device__ __forceinline__ unsigned short f2bf(float x) {
    unsigned u = __float_as_uint(x);
    unsigned r = u + 0x7FFFu + ((u >> 16) & 1u);
    return (unsigned short)(r >> 16);
}
__device__ __forceinline__ float bf2f(unsigned short h) {
    return __uint_as_float(((unsigned)h) << 16);
}

__device__ __forceinline__ floatx4 mfma16(bf16x8 a, bf16x8 b, floatx4 c) {
    return __builtin_amdgcn_mfma_f32_16x16x32_bf16(a, b, c, 0, 0, 0);
}

// pack 8 floats -> hi/lo bf16 octets, store as uint4 at short-offset off
__device__ __forceinline__ void store_octets(unsigned short* hiP, unsigned short* loP,
                                             int off, const float* v) {
    unsigned hs[8], ls[8];
    #pragma unroll
    for (int j = 0; j < 8; ++j) {
        unsigned short h = f2bf(v[j]);
        float r = v[j] - bf2f(h);
        hs[j] = h; ls[j] = f2bf(r);
    }
    uint4 ph, pl;
    ph.x = hs[0] | (hs[1] << 16); ph.y = hs[2] | (hs[3] << 16);
    ph.z = hs[4] | (hs[5] << 16); ph.w = hs[6] | (hs[7] << 16);
    pl.x = ls[0] | (ls[1] << 16); pl.y = ls[2] | (ls[3] << 16);
    pl.z = ls[4] | (ls[5] << 16); pl.w = ls[6] | (ls[7] << 16);
    *(uint4*)(hiP + off) = ph;
    *(uint4*)(loP + off) = pl;
}

struct Acc { floatx4 t[2][2]; };

__device__ __forceinline__ void acc_zero(Acc& a) {
    #pragma unroll
    for (int mi = 0; mi < 2; ++mi)
        #pragma unroll
        for (int ni = 0; ni < 2; ++ni)
            a.t[mi][ni] = (floatx4){0.f, 0.f, 0.f, 0.f};
}

// D += (Ahi+Alo)@(Bhi+Blo) approx, 12 MFMAs. fo = n16*32 + ((q^sw)<<3)
__device__ __forceinline__ void mm_bf16x3(const unsigned short* AhiP, const unsigned short* AloP,
                                          const unsigned short* BhiP, const unsigned short* BloP,
                                          int fo, Acc& acc) {
    bf16x8 ah0 = *(const bf16x8*)(AhiP + fo);
    bf16x8 ah1 = *(const bf16x8*)(AhiP + fo + 512);
    bf16x8 al0 = *(const bf16x8*)(AloP + fo);
    bf16x8 al1 = *(const bf16x8*)(AloP + fo + 512);
    bf16x8 bh0 = *(const bf16x8*)(BhiP + fo);
    bf16x8 bh1 = *(const bf16x8*)(BhiP + fo + 512);
    bf16x8 bl0 = *(const bf16x8*)(BloP + fo);
    bf16x8 bl1 = *(const bf16x8*)(BloP + fo + 512);
    acc.t[0][0] = mfma16(ah0, bh0, acc.t[0][0]);
    acc.t[0][0] = mfma16(ah0, bl0, acc.t[0][0]);
    acc.t[0][0] = mfma16(al0, bh0, acc.t[0][0]);
    acc.t[0][1] = mfma16(ah0, bh1, acc.t[0][1]);
    acc.t[0][1] = mfma16(ah0, bl1, acc.t[0][1]);
    acc.t[0][1] = mfma16(al0, bh1, acc.t[0][1]);
    acc.t[1][0] = mfma16(ah1, bh0, acc.t[1][0]);
    acc.t[1][0] = mfma16(ah1, bl0, acc.t[1][0]);
    acc.t[1][0] = mfma16(al1, bh0, acc.t[1][0]);
    acc.t[1][1] = mfma16(ah1, bh1, acc.t[1][1]);
    acc.t[1][1] = mfma16(ah1, bl1, acc.t[1][1]);
    acc.t[1][1] = mfma16(al1, bh1, acc.t[1][1]);
}

// write D (C-layout regs, D[m][n]) in B-conv: slot=n, pos=m ; b64 stores
__device__ __forceinline__ void writeX(unsigned short* Xh, unsigned short* Xl,
                                       const Acc& acc, int n16, int q, int sw) {
    const int q1 = q >> 1, q0 = q & 1;
    #pragma unroll
    for (int mi = 0; mi < 2; ++mi)
        #pragma unroll
        for (int ni = 0; ni < 2; ++ni) {
            floatx4 a = acc.t[mi][ni];
            int g   = mi * 2 + q1;                         // m>>3
            int off = ni * 512 + n16 * 32 + ((g ^ sw) << 3) + q0 * 4;
            unsigned h[4], l[4];
            #pragma unroll
            for (int r = 0; r < 4; ++r) {
                unsigned short hh = f2bf(a[r]);
                h[r] = hh;
                l[r] = f2bf(a[r] - bf2f(hh));
            }
            uint2 uh, ul;
            uh.x = h[0] | (h[1] << 16); uh.y = h[2] | (h[3] << 16);
            ul.x = l[0] | (l[1] << 16); ul.y = l[2] | (l[3] << 16);
            *(uint2*)(Xh + off) = uh;
            *(uint2*)(Xl + off) = ul;
        }
}

// write D (C-layout regs, D[m][n]) in A-conv: slot=m, pos=n ; scalar b16 stores
__device__ __forceinline__ void writeX_Aconv(unsigned short* Xh, unsigned short* Xl,
                                             const Acc& acc, int n16, int q) {
    #pragma unroll
    for (int mi = 0; mi < 2; ++mi)
        #pragma unroll
        for (int ni = 0; ni < 2; ++ni) {
            floatx4 a = acc.t[mi][ni];
            #pragma unroll
            for (int r = 0; r < 4; ++r) {
                int m   = q * 4 + r;                       // m & 15 ; m&3 == r
                int n   = ni * 16 + n16;
                int off = mi * 512 + m * 32 + (((n >> 3) ^ r) << 3) + (n & 7);
                float v = a[r];
                unsigned short hh = f2bf(v);
                Xh[off] = hh;
                Xl[off] = f2bf(v - bf2f(hh));
            }
        }
}

// prefetch M(idx) column-slice: pf[t] = M[16h+t][c], zero-padded
__device__ __forceinline__ void loadA_pref(const float* Mg, int lane, float* pf) {
    const int c = lane & 31;
    const int h = lane >> 5;
    const bool cok = (c < MD);
    #pragma unroll
    for (int t = 0; t < 16; ++t) {
        int r = h * 16 + t;
        pf[t] = (cok && r < MD) ? Mg[(size_t)r * MD + c] : 0.f;
    }
}

// commit pf (A[m=c][k=r] = M^T) into A planes (A-conv)
__device__ __forceinline__ void commitA(unsigned short* Ah, unsigned short* Al,
                                        const float* pf, int lane) {
    const int c   = lane & 31;
    const int h   = lane >> 5;
    const int mt  = c >> 4;
    const int m16 = c & 15;
    const int sw  = c & 3;
    #pragma unroll
    for (int s = 0; s < 2; ++s) {
        int g   = 2 * h + s;
        int off = mt * 512 + m16 * 32 + ((g ^ sw) << 3);
        store_octets(Ah, Al, off, pf + 8 * s);
    }
}

__global__ __launch_bounds__(256, 4)
void cmow_mfma_kernel(const int* __restrict__ sent,
                      const float* __restrict__ table,
                      float* __restrict__ out)
{
    __shared__ __align__(16) unsigned short smem[4 * 4096];

    const int tid  = threadIdx.x;
    const int lane = tid & 63;
    const int w    = tid >> 6;
    const int b    = blockIdx.x;

    unsigned short* Ahi = smem + w * 4096;         // A-conv plane (staged M^T)
    unsigned short* Alo = Ahi + 1024;
    unsigned short* Xhi = Ahi + 2048;              // B-conv plane (running X)
    unsigned short* Xlo = Ahi + 3072;

    const int* sp = sent + b * SEQL + w * CHUNK;
    int idx[CHUNK];
    #pragma unroll
    for (int i = 0; i < CHUNK; ++i) idx[i] = sp[i];

    const int n16 = lane & 15;
    const int q   = lane >> 4;
    const int sw  = lane & 3;
    const int fo  = n16 * 32 + ((q ^ sw) << 3);    // fragment read offset (+0/512 per tile)

    // ---- stage X0 = M(idx0)^T in B-conv: slot=n (=M row), pos=k (=M col)
    {
        const int nr = lane & 31;
        const int h  = lane >> 5;
        const int nt = nr >> 4;
        float v[16];
        #pragma unroll
        for (int t = 0; t < 16; ++t) v[t] = 0.f;
        if (nr < MD) {
            const float* src = table + (size_t)idx[0] * MD2 + nr * MD + 16 * h;
            const int nval = (h == 0) ? 16 : 12;
            #pragma unroll
            for (int t = 0; t < 16; t += 4) {
                if (t < nval) {
                    float4 f = *(const float4*)(src + t);
                    v[t] = f.x; v[t+1] = f.y; v[t+2] = f.z; v[t+3] = f.w;
                }
            }
        }
        #pragma unroll
        for (int s = 0; s < 2; ++s) {
            int g   = 2 * h + s;
            int off = nt * 512 + n16 * 32 + ((g ^ sw) << 3);
            store_octets(Xhi, Xlo, off, v + 8 * s);
        }
    }

    // ---- phase 1: 15 chained steps X = M_i^T @ X (wave-private)
    float pf[16];
    loadA_pref(table + (size_t)idx[1] * MD2, lane, pf);

    for (int i = 1; i < CHUNK; ++i) {
        commitA(Ahi, Alo, pf, lane);
        if (i + 1 < CHUNK)
            loadA_pref(table + (size_t)idx[i + 1] * MD2, lane, pf);

        LDS_FENCE();   // A-writes (this step) + X-writes (prev step) visible

        Acc acc; acc_zero(acc);
        mm_bf16x3(Ahi, Alo, Xhi, Xlo, fo, acc);

        if (i < CHUNK - 1) {
            writeX(Xhi, Xlo, acc, n16, q, sw);
        } else {
            // final chunk product X_w: waves 0,2 -> B-conv (future B operand);
            // waves 1,3 -> A-conv into own A planes (future A operand)
            if ((w & 1) == 0) writeX(Xhi, Xlo, acc, n16, q, sw);
            else              writeX_Aconv(Ahi, Alo, acc, n16, q);
        }
    }

    // ---- phase 2: tree combine (X_w = P_w^T)
    __syncthreads();

    if (w < 2) {
        // wave w: Y_w = X_{2w+1} @ X_{2w} = (P_{2w} P_{2w+1})^T
        const unsigned short* pAh = smem + (2 * w + 1) * 4096;          // A-conv X_{2w+1}
        const unsigned short* pAl = pAh + 1024;
        const unsigned short* pBh = smem + (2 * w) * 4096 + 2048;       // B-conv X_{2w}
        const unsigned short* pBl = pBh + 1024;
        Acc acc; acc_zero(acc);
        mm_bf16x3(pAh, pAl, pBh, pBl, fo, acc);
        if (w == 0) {
            writeX(smem + 0, smem + 1024, acc, n16, q, sw);             // Y0 B-conv, wave0 A-plane space (dead)
        } else {
            writeX_Aconv(smem + 4096 + 2048, smem + 4096 + 3072, acc, n16, q);  // Y1 A-conv, wave1 X-plane space (dead)
        }
    }
    __syncthreads();

    if (w == 0) {
        // final^T = Y1 @ Y0
        const unsigned short* pAh = smem + 4096 + 2048;
        const unsigned short* pAl = smem + 4096 + 3072;
        const unsigned short* pBh = smem + 0;
        const unsigned short* pBl = smem + 1024;
        Acc acc; acc_zero(acc);
        mm_bf16x3(pAh, pAl, pBh, pBl, fo, acc);

        // out[C][R] = final^T[R... ] : acc holds final^T => out[n][m] over regs m
        float* op = out + (size_t)b * MD2;
        #pragma unroll
        for (int mi = 0; mi < 2; ++mi)
            #pragma unroll
            for (int ni = 0; ni < 2; ++ni) {
                int C = ni * 16 + n16;       // cur row (= n of final^T)
                int R = mi * 16 + q * 4;     // cur col base (= m of final^T)
                if (C < MD && R + 3 < MD) {
                    floatx4 a = acc.t[mi][ni];
                    float4 st; st.x = a[0]; st.y = a[1]; st.z = a[2]; st.w = a[3];
                    *(float4*)(op + C * MD + R) = st;
                }
            }
    }
}

extern "C" void kernel_launch(void* const* d_in, const int* in_sizes, int n_in,
                              void* d_out, int out_size, void* d_ws, size_t ws_size,
                              hipStream_t stream) {
    const int*   sent  = (const int*)d_in[0];
    const float* table = (const float*)d_in[1];
    float*       outp  = (float*)d_out;

    const int batch = in_sizes[0] / SEQL;   // 1024
    cmow_mfma_kernel<<<dim3(batch), dim3(256), 0, stream>>>(sent, table, outp);
}

// Round 5
// 174.547 us; speedup vs baseline: 1.4367x; 1.1297x over previous
//
#include <hip/hip_runtime.h>
#include <hip/hip_bf16.h>

// CMOW word-matrix chain product — R5: reg-resident A, packed cvt, fixed swizzle.
// sent: [1024,64] int32 ; table: [30001,784] fp32 ; out: [1024,784] fp32
//
// X = cur^T chain, X_new = M^T @ X via mfma_f32_16x16x32_bf16 (32x32 padded,
// 2x2 tiles, K=32 in one instr), fp32 ~ hi+lo bf16, 3 products/tile.
// A (=M^T) is prefetched from global DIRECTLY in A-frag pattern
//   (lane: a[j] = M[8q+j][m], m = n16 / 16+n16) -> no LDS for A at all.
// X round-trips LDS in B-conv with conflict-free swizzle:
//   addr(n,g,h) = n*64 + ((h^(n&1))<<5) + ((g^((n>>1)&3))<<3)   [shorts]
//   bank-quad = 16*(h^(n&1)) + 4*(g^((n>>1)&3)) -> 8 consecutive lanes hit
//   8 distinct quads (R4's sw=n&3 had period-4 -> 10M conflict cycles).
// Conversions via v_cvt_pk_bf16_f32 (__float22bfloat162_rn).

#define MD    28
#define MD2   784
#define SEQL  64
#define CHUNK 16

typedef __attribute__((ext_vector_type(8))) short bf16x8;
typedef __attribute__((ext_vector_type(4))) float floatx4;

#define LDS_FENCE() asm volatile("s_waitcnt lgkmcnt(0)" ::: "memory")

__device__ __forceinline__ unsigned short f2bf(float x) {
    unsigned u = __float_as_uint(x);
    unsigned r = u + 0x7FFFu + ((u >> 16) & 1u);
    return (unsigned short)(r >> 16);
}
__device__ __forceinline__ float bf2f(unsigned short h) {
    return __uint_as_float(((unsigned)h) << 16);
}

// pack 2 fp32 -> 1 dword of 2 bf16 (RNE), v_cvt_pk_bf16_f32 on gfx950
__device__ __forceinline__ unsigned pk_bf16(float x, float y) {
    float2 f; f.x = x; f.y = y;
    __hip_bfloat162 h2 = __float22bfloat162_rn(f);
    union { __hip_bfloat162 h; unsigned u; } cv; cv.h = h2;
    return cv.u;
}

union U4F { uint4 u; bf16x8 v; };

// 8 fp32 -> hi/lo bf16x8
__device__ __forceinline__ void pack8(const float* v, bf16x8* hi, bf16x8* lo) {
    U4F H, L;
    unsigned* ph = (unsigned*)&H.u;
    unsigned* pl = (unsigned*)&L.u;
    #pragma unroll
    for (int p = 0; p < 4; ++p) {
        float x = v[2*p], y = v[2*p+1];
        unsigned h = pk_bf16(x, y);
        float rx = x - __uint_as_float(h << 16);
        float ry = y - __uint_as_float(h & 0xffff0000u);
        pl[p] = pk_bf16(rx, ry);
        ph[p] = h;
    }
    *hi = H.v; *lo = L.v;
}

// X-plane address (shorts): slot n (0..31), k-octet g (0..3), h (0=hi,1=lo)
__device__ __forceinline__ int xaddr(int n, int g, int h) {
    return n * 64 + ((h ^ (n & 1)) << 5) + ((g ^ ((n >> 1) & 3)) << 3);
}

struct Acc { floatx4 t[2][2]; };

__device__ __forceinline__ void acc_zero(Acc& a) {
    #pragma unroll
    for (int mi = 0; mi < 2; ++mi)
        #pragma unroll
        for (int ni = 0; ni < 2; ++ni)
            a.t[mi][ni] = (floatx4){0.f, 0.f, 0.f, 0.f};
}

__device__ __forceinline__ floatx4 mfma16(bf16x8 a, bf16x8 b, floatx4 c) {
    return __builtin_amdgcn_mfma_f32_16x16x32_bf16(a, b, c, 0, 0, 0);
}

__device__ __forceinline__ void mm12(bf16x8 ah0, bf16x8 ah1, bf16x8 al0, bf16x8 al1,
                                     bf16x8 bh0, bf16x8 bh1, bf16x8 bl0, bf16x8 bl1,
                                     Acc& acc) {
    acc.t[0][0] = mfma16(ah0, bh0, acc.t[0][0]);
    acc.t[0][1] = mfma16(ah0, bh1, acc.t[0][1]);
    acc.t[1][0] = mfma16(ah1, bh0, acc.t[1][0]);
    acc.t[1][1] = mfma16(ah1, bh1, acc.t[1][1]);
    acc.t[0][0] = mfma16(ah0, bl0, acc.t[0][0]);
    acc.t[0][1] = mfma16(ah0, bl1, acc.t[0][1]);
    acc.t[1][0] = mfma16(ah1, bl0, acc.t[1][0]);
    acc.t[1][1] = mfma16(ah1, bl1, acc.t[1][1]);
    acc.t[0][0] = mfma16(al0, bh0, acc.t[0][0]);
    acc.t[0][1] = mfma16(al0, bh1, acc.t[0][1]);
    acc.t[1][0] = mfma16(al1, bh0, acc.t[1][0]);
    acc.t[1][1] = mfma16(al1, bh1, acc.t[1][1]);
}

// B-frags from X plane (4x ds_read_b128)
__device__ __forceinline__ void readB(const unsigned short* X, int n16, int q,
                                      bf16x8* bh0, bf16x8* bh1, bf16x8* bl0, bf16x8* bl1) {
    *bh0 = *(const bf16x8*)(X + xaddr(n16,      q, 0));
    *bl0 = *(const bf16x8*)(X + xaddr(n16,      q, 1));
    *bh1 = *(const bf16x8*)(X + xaddr(16 + n16, q, 0));
    *bl1 = *(const bf16x8*)(X + xaddr(16 + n16, q, 1));
}

// D (C-layout) -> X plane B-conv (8x ds_write_b64)
__device__ __forceinline__ void writeX(unsigned short* X, const Acc& acc,
                                       int n16, int q) {
    const int sub = (q & 1) * 4;
    #pragma unroll
    for (int mi = 0; mi < 2; ++mi) {
        const int g = 2 * mi + (q >> 1);
        #pragma unroll
        for (int ni = 0; ni < 2; ++ni) {
            floatx4 a = acc.t[mi][ni];
            const int n = ni * 16 + n16;
            unsigned h0 = pk_bf16(a[0], a[1]);
            unsigned h1 = pk_bf16(a[2], a[3]);
            float r0 = a[0] - __uint_as_float(h0 << 16);
            float r1 = a[1] - __uint_as_float(h0 & 0xffff0000u);
            float r2 = a[2] - __uint_as_float(h1 << 16);
            float r3 = a[3] - __uint_as_float(h1 & 0xffff0000u);
            unsigned l0 = pk_bf16(r0, r1);
            unsigned l1 = pk_bf16(r2, r3);
            uint2 uh; uh.x = h0; uh.y = h1;
            uint2 ul; ul.x = l0; ul.y = l1;
            *(uint2*)(X + xaddr(n, g, 0) + sub) = uh;
            *(uint2*)(X + xaddr(n, g, 1) + sub) = ul;
        }
    }
}

// D (C-layout) -> A-conv scratch (plain m*32+n layout, hi | lo+1024), once/chain
__device__ __forceinline__ void writeA_scratch(unsigned short* S, const Acc& acc,
                                               int n16, int q) {
    unsigned short* Sh = S;
    unsigned short* Sl = S + 1024;
    #pragma unroll
    for (int mi = 0; mi < 2; ++mi)
        #pragma unroll
        for (int ni = 0; ni < 2; ++ni) {
            floatx4 a = acc.t[mi][ni];
            #pragma unroll
            for (int r = 0; r < 4; ++r) {
                int m = mi * 16 + q * 4 + r;
                int n = ni * 16 + n16;
                int off = m * 32 + n;
                unsigned short hh = f2bf(a[r]);
                Sh[off] = hh;
                Sl[off] = f2bf(a[r] - bf2f(hh));
            }
        }
}

__device__ __forceinline__ void readA_scratch(const unsigned short* S, int n16, int q,
                                              bf16x8* ah0, bf16x8* ah1,
                                              bf16x8* al0, bf16x8* al1) {
    const unsigned short* Sh = S;
    const unsigned short* Sl = S + 1024;
    const int o0 = n16 * 32 + 8 * q;
    const int o1 = (16 + n16) * 32 + 8 * q;
    *ah0 = *(const bf16x8*)(Sh + o0);
    *ah1 = *(const bf16x8*)(Sh + o1);
    *al0 = *(const bf16x8*)(Sl + o0);
    *al1 = *(const bf16x8*)(Sl + o1);
}

// prefetch M in A-frag pattern: pa[j]=M[8q+j][n16], pb[j]=M[8q+j][16+n16]
__device__ __forceinline__ void prefA(const float* __restrict__ Mg, int n16, int q,
                                      float* pa, float* pb) {
    const bool bok = (n16 < MD - 16);
    #pragma unroll
    for (int j = 0; j < 8; ++j) {
        int k = 8 * q + j;
        bool kv = (k < MD);
        pa[j] = kv ? Mg[k * MD + n16] : 0.f;
        pb[j] = (kv && bok) ? Mg[k * MD + 16 + n16] : 0.f;
    }
}

__global__ __launch_bounds__(256, 4)
void cmow_mfma_kernel(const int* __restrict__ sent,
                      const float* __restrict__ table,
                      float* __restrict__ out)
{
    // [0,8192): X planes, 2048 shorts/wave. [8192,12288): A-conv scratch x2.
    __shared__ __align__(16) unsigned short smem[12288];

    const int tid  = threadIdx.x;
    const int lane = tid & 63;
    const int w    = tid >> 6;
    const int b    = blockIdx.x;

    unsigned short* Xw = smem + w * 2048;

    const int* sp = sent + b * SEQL + w * CHUNK;
    int idx[CHUNK];
    #pragma unroll
    for (int i = 0; i < CHUNK; ++i) idx[i] = sp[i];

    const int n16 = lane & 15;
    const int q   = lane >> 4;

    // ---- stage X0 = M(idx0)^T in B-conv: slot n = M row, pos k = M col
    {
        const int nr = lane & 31;
        const int h2 = lane >> 5;
        float v[16];
        #pragma unroll
        for (int t = 0; t < 16; ++t) v[t] = 0.f;
        if (nr < MD) {
            const float* src = table + (size_t)idx[0] * MD2 + nr * MD + 16 * h2;
            const int nval = (h2 == 0) ? 16 : 12;
            #pragma unroll
            for (int t = 0; t < 16; t += 4) {
                if (t < nval) {
                    float4 f = *(const float4*)(src + t);
                    v[t] = f.x; v[t+1] = f.y; v[t+2] = f.z; v[t+3] = f.w;
                }
            }
        }
        #pragma unroll
        for (int s = 0; s < 2; ++s) {
            bf16x8 hi, lo;
            pack8(v + 8 * s, &hi, &lo);
            int g = 2 * h2 + s;
            *(bf16x8*)(Xw + xaddr(nr, g, 0)) = hi;
            *(bf16x8*)(Xw + xaddr(nr, g, 1)) = lo;
        }
    }

    float pa[8], pb[8];
    prefA(table + (size_t)idx[1] * MD2, n16, q, pa, pb);
    LDS_FENCE();

    // ---- phase 1: 15 chained steps X = M_i^T @ X (wave-private)
    for (int i = 1; i < CHUNK; ++i) {
        // A-frags from prefetched registers
        bf16x8 ah0, ah1, al0, al1;
        pack8(pa, &ah0, &al0);
        pack8(pb, &ah1, &al1);
        if (i + 1 < CHUNK)
            prefA(table + (size_t)idx[i + 1] * MD2, n16, q, pa, pb);

        bf16x8 bh0, bh1, bl0, bl1;
        readB(Xw, n16, q, &bh0, &bh1, &bl0, &bl1);

        Acc acc; acc_zero(acc);
        mm12(ah0, ah1, al0, al1, bh0, bh1, bl0, bl1, acc);

        if (i < CHUNK - 1 || (w & 1) == 0)
            writeX(Xw, acc, n16, q);                          // B-conv (own plane)
        else
            writeA_scratch(smem + 8192 + (w >> 1) * 2048, acc, n16, q);  // waves 1,3
        LDS_FENCE();
    }

    // ---- phase 2: tree combine (X_w = P_w^T)
    __syncthreads();

    if (w < 2) {
        // Y_w = X_{2w+1} @ X_{2w} = (P_{2w} P_{2w+1})^T
        bf16x8 ah0, ah1, al0, al1, bh0, bh1, bl0, bl1;
        readA_scratch(smem + 8192 + w * 2048, n16, q, &ah0, &ah1, &al0, &al1);
        readB(smem + (2 * w) * 2048, n16, q, &bh0, &bh1, &bl0, &bl1);
        Acc acc; acc_zero(acc);
        mm12(ah0, ah1, al0, al1, bh0, bh1, bl0, bl1, acc);
        if (w == 0) writeX(smem, acc, n16, q);                      // Y0 -> wave0 X plane
        else        writeA_scratch(smem + 8192 + 2048, acc, n16, q); // Y1 -> slot1 (own reads done)
    }
    __syncthreads();

    if (w == 0) {
        // final^T = Y1 @ Y0
        bf16x8 ah0, ah1, al0, al1, bh0, bh1, bl0, bl1;
        readA_scratch(smem + 8192 + 2048, n16, q, &ah0, &ah1, &al0, &al1);
        readB(smem, n16, q, &bh0, &bh1, &bl0, &bl1);
        Acc acc; acc_zero(acc);
        mm12(ah0, ah1, al0, al1, bh0, bh1, bl0, bl1, acc);

        float* op = out + (size_t)b * MD2;
        #pragma unroll
        for (int mi = 0; mi < 2; ++mi)
            #pragma unroll
            for (int ni = 0; ni < 2; ++ni) {
                int C = ni * 16 + n16;       // cur row (= n of final^T)
                int R = mi * 16 + q * 4;     // cur col base (= m of final^T)
                if (C < MD && R + 3 < MD) {
                    floatx4 a = acc.t[mi][ni];
                    float4 st; st.x = a[0]; st.y = a[1]; st.z = a[2]; st.w = a[3];
                    *(float4*)(op + C * MD + R) = st;
                }
            }
    }
}

extern "C" void kernel_launch(void* const* d_in, const int* in_sizes, int n_in,
                              void* d_out, int out_size, void* d_ws, size_t ws_size,
                              hipStream_t stream) {
    const int*   sent  = (const int*)d_in[0];
    const float* table = (const float*)d_in[1];
    float*       outp  = (float*)d_out;

    const int batch = in_sizes[0] / SEQL;   // 1024
    cmow_mfma_kernel<<<dim3(batch), dim3(256), 0, stream>>>(sent, table, outp);
}